// Round 1
// baseline (181.597 us; speedup 1.0000x reference)
//
#include <hip/hip_runtime.h>
#include <cstddef>

#define SSM_N 64
#define SSM_H 256
#define SSM_B 8
#define SSM_L 1024
#define PAD   68   // row stride (floats) for 64x64 LDS matrices; 68*4=272 bytes, 16B-aligned rows
#define CPAD  65   // row stride for 32x64 row buffers (breaks stride-64 bank conflict)

// acc[16] += Arow[k] * Bmat[k][j0..j0+15], k = 0..63. Bmat reads are wave-uniform
// broadcast float4 loads (16B aligned because PAD*4 % 16 == 0 and j0 % 4 == 0).
__device__ __forceinline__ void mat_acc16(const float* Arow, const float* Bmat,
                                          int j0, float acc[16])
{
    #pragma unroll 4
    for (int k = 0; k < SSM_N; ++k) {
        const float a = Arow[k];
        const float4* bp = reinterpret_cast<const float4*>(Bmat + k * PAD + j0);
        const float4 b0 = bp[0];
        const float4 b1 = bp[1];
        const float4 b2 = bp[2];
        const float4 b3 = bp[3];
        acc[0]  += a * b0.x; acc[1]  += a * b0.y; acc[2]  += a * b0.z; acc[3]  += a * b0.w;
        acc[4]  += a * b1.x; acc[5]  += a * b1.y; acc[6]  += a * b1.z; acc[7]  += a * b1.w;
        acc[8]  += a * b2.x; acc[9]  += a * b2.y; acc[10] += a * b2.z; acc[11] += a * b2.w;
        acc[12] += a * b3.x; acc[13] += a * b3.y; acc[14] += a * b3.z; acc[15] += a * b3.w;
    }
}

// One block per channel h. 256 threads = 4 waves; wave q owns columns [16q, 16q+16).
__global__ __launch_bounds__(256) void ssm_prep_kernel(
    const float* __restrict__ As, const float* __restrict__ Bsin,
    const float* __restrict__ Csin, const float* __restrict__ logsteps,
    float* __restrict__ Kout)
{
    __shared__ __align__(16) float MB[SSM_N * PAD];
    __shared__ __align__(16) float TB[SSM_N * PAD];
    __shared__ float CallL[32 * CPAD];
    __shared__ float XallL[32 * CPAD];
    __shared__ float pbuf[4 * 64];
    __shared__ float bvec[64];

    const int h    = blockIdx.x;
    const int tid  = threadIdx.x;
    const int lane = tid & 63;
    const int q    = tid >> 6;
    const int j0   = q * 16;

    const float step = expf(logsteps[h]);
    const float s    = 0.5f * step;

    // ---- 1. load M = s*A into MB ----
    const float* Ah = As + (size_t)h * SSM_N * SSM_N;
    #pragma unroll
    for (int r = 0; r < 16; ++r) {
        int e = r * 256 + tid;
        MB[(e >> 6) * PAD + (e & 63)] = s * Ah[e];
    }
    __syncthreads();

    // ---- 2. Horner Neumann: TB = S = M + M^2 + M^3 + M^4 ----
    // out = M + M*Bop. In-place on TB is safe: each wave reads/writes only its
    // own 16-column block of TB (A-operand is MB, read-only). No inter-iter barrier.
    for (int it = 0; it < 3; ++it) {
        float acc[16];
        #pragma unroll
        for (int jj = 0; jj < 16; ++jj) acc[jj] = 0.f;
        const float* Bop = (it == 0) ? MB : TB;
        mat_acc16(MB + lane * PAD, Bop, j0, acc);
        const float4* mp = reinterpret_cast<const float4*>(MB + lane * PAD + j0);
        const float4 m0 = mp[0], m1 = mp[1], m2 = mp[2], m3 = mp[3];
        acc[0]  += m0.x; acc[1]  += m0.y; acc[2]  += m0.z; acc[3]  += m0.w;
        acc[4]  += m1.x; acc[5]  += m1.y; acc[6]  += m1.z; acc[7]  += m1.w;
        acc[8]  += m2.x; acc[9]  += m2.y; acc[10] += m2.z; acc[11] += m2.w;
        acc[12] += m3.x; acc[13] += m3.y; acc[14] += m3.z; acc[15] += m3.w;
        float4* wp = reinterpret_cast<float4*>(TB + lane * PAD + j0);
        wp[0] = make_float4(acc[0],  acc[1],  acc[2],  acc[3]);
        wp[1] = make_float4(acc[4],  acc[5],  acc[6],  acc[7]);
        wp[2] = make_float4(acc[8],  acc[9],  acc[10], acc[11]);
        wp[3] = make_float4(acc[12], acc[13], acc[14], acc[15]);
    }
    __syncthreads();

    // ---- 3. AbT into MB (M is dead): AbT[j][i] = Ab[i][j] = 2*S[i][j] + delta ----
    #pragma unroll
    for (int r = 0; r < 16; ++r) {
        int e = r * 256 + tid;
        int i = e >> 6, j = e & 63;
        MB[j * PAD + i] = 2.f * TB[i * PAD + j] + ((i == j) ? 1.f : 0.f);
    }
    // ---- 4. Bb = step*(b + S b)  (wave 0);  Call row 0 = Cs  (wave 1) ----
    if (q == 0) {
        pbuf[lane] = Bsin[h * SSM_N + lane];
        float accb = 0.f;
        #pragma unroll 4
        for (int k = 0; k < SSM_N; ++k)
            accb += TB[lane * PAD + k] * pbuf[k];
        bvec[lane] = step * (pbuf[lane] + accb);
    } else if (q == 1) {
        CallL[lane] = Csin[h * SSM_N + lane];
    }
    __syncthreads();

    // ---- 5. c-chain: c_{j+1} = c_j * Ab = c_j + 2*(c_j * S), S = TB ----
    for (int j = 0; j < 31; ++j) {
        const float* crow = CallL + j * CPAD;
        float p = 0.f;
        #pragma unroll
        for (int kk = 0; kk < 16; ++kk) {
            int k = j0 + kk;
            p += crow[k] * TB[k * PAD + lane];   // column read: 2-way bank alias, free
        }
        pbuf[q * 64 + lane] = p;
        __syncthreads();
        if (q == 0) {
            CallL[(j + 1) * CPAD + lane] =
                crow[lane] + 2.f * (pbuf[lane] + pbuf[64 + lane] + pbuf[128 + lane] + pbuf[192 + lane]);
        }
        __syncthreads();
    }

    // ---- 6. five squarings: PT = (AbT)^32. Ping-pong MB <-> TB, final in TB ----
    {
        float* src = MB;
        float* dst = TB;
        for (int it = 0; it < 5; ++it) {
            float acc[16];
            #pragma unroll
            for (int jj = 0; jj < 16; ++jj) acc[jj] = 0.f;
            mat_acc16(src + lane * PAD, src, j0, acc);
            float4* wp = reinterpret_cast<float4*>(dst + lane * PAD + j0);
            wp[0] = make_float4(acc[0],  acc[1],  acc[2],  acc[3]);
            wp[1] = make_float4(acc[4],  acc[5],  acc[6],  acc[7]);
            wp[2] = make_float4(acc[8],  acc[9],  acc[10], acc[11]);
            wp[3] = make_float4(acc[12], acc[13], acc[14], acc[15]);
            __syncthreads();
            float* tmp = src; src = dst; dst = tmp;
        }
        // PT now lives in TB (it4 wrote TB).
    }

    // ---- 7. x-chain: x_0 = Bb; x_{m+1}[i] = sum_k PT[k][i] * x_m[k] ----
    if (q == 0) XallL[lane] = bvec[lane];
    __syncthreads();
    for (int m = 0; m < 31; ++m) {
        const float* xrow = XallL + m * CPAD;
        float p = 0.f;
        #pragma unroll
        for (int kk = 0; kk < 16; ++kk) {
            int k = j0 + kk;
            p += xrow[k] * TB[k * PAD + lane];
        }
        pbuf[q * 64 + lane] = p;
        __syncthreads();
        if (q == 0)
            XallL[(m + 1) * CPAD + lane] =
                pbuf[lane] + pbuf[64 + lane] + pbuf[128 + lane] + pbuf[192 + lane];
        __syncthreads();
    }

    // ---- 8. K[32m + j][h] = dot(Call[j], Xall[m]) ----
    #pragma unroll
    for (int r = 0; r < 4; ++r) {
        int l  = r * 256 + tid;
        int mm = l >> 5, jj = l & 31;
        const float* cr = CallL + jj * CPAD;
        const float* xr = XallL + mm * CPAD;
        float sacc = 0.f;
        #pragma unroll 4
        for (int i = 0; i < SSM_N; ++i) sacc += cr[i] * xr[i];
        Kout[(size_t)l * SSM_H + h] = sacc;
    }
}

// Causal conv: y[b,l,h] = sum_{d=0}^{l} K[d,h]*u[b,l-d,h] + Ds[h]*u[b,l,h].
// thread = h (coalesced). Each block: one b, tile pair (p, 63-p) of 16 rows each
// -> every block does exactly 1040 inner steps (uniform load balance).
// b = blockIdx & 7 pins each batch slice to one XCD's L2 (1MB u + 1MB K < 4MB).
__global__ __launch_bounds__(256) void ssm_conv_kernel(
    const float* __restrict__ U, const float* __restrict__ Kk,
    const float* __restrict__ Ds, float* __restrict__ Y)
{
    const int h = threadIdx.x;
    const int b = blockIdx.x & 7;
    const int p = blockIdx.x >> 3;
    const float dh = Ds[h];
    const float* Ub = U + (size_t)b * SSM_L * SSM_H + h;
    float* Yb = Y + (size_t)b * SSM_L * SSM_H + h;

    #pragma unroll
    for (int half = 0; half < 2; ++half) {
        const int t  = (half == 0) ? p : (63 - p);
        const int l0 = t << 4;
        const int nd = l0 + 16;
        float acc[16], uw[16], u0[16];
        #pragma unroll
        for (int i = 0; i < 16; ++i) {
            float v = Ub[(l0 + i) * SSM_H];
            acc[i] = 0.f; uw[i] = v; u0[i] = v;
        }
        for (int d0 = 0; d0 < nd; d0 += 16) {
            #pragma unroll
            for (int dd = 0; dd < 16; ++dd) {
                const int d = d0 + dd;
                const float kv = Kk[d * SSM_H + h];
                #pragma unroll
                for (int i = 0; i < 16; ++i) acc[i] += kv * uw[i];
                const int li = l0 - 1 - d;               // next u entering the window
                const float nu = (li >= 0) ? Ub[li * SSM_H] : 0.f;
                #pragma unroll
                for (int i = 15; i > 0; --i) uw[i] = uw[i - 1];
                uw[0] = nu;
            }
        }
        #pragma unroll
        for (int i = 0; i < 16; ++i)
            Yb[(l0 + i) * SSM_H] = acc[i] + dh * u0[i];
    }
}

extern "C" void kernel_launch(void* const* d_in, const int* in_sizes, int n_in,
                              void* d_out, int out_size, void* d_ws, size_t ws_size,
                              hipStream_t stream)
{
    const float* inp     = (const float*)d_in[0];  // (B,L,H)
    const float* As      = (const float*)d_in[1];  // (H,N,N)
    const float* Bsin    = (const float*)d_in[2];  // (H,N,1)
    const float* Csin    = (const float*)d_in[3];  // (H,1,N)
    const float* Dsin    = (const float*)d_in[4];  // (H,)
    const float* lsteps  = (const float*)d_in[5];  // (H,)
    float* Y    = (float*)d_out;                   // (B,L,H)
    float* Kbuf = (float*)d_ws;                    // (L,H) = 1 MB scratch

    ssm_prep_kernel<<<dim3(SSM_H), dim3(256), 0, stream>>>(As, Bsin, Csin, lsteps, Kbuf);
    ssm_conv_kernel<<<dim3(SSM_B * 32), dim3(256), 0, stream>>>(inp, Kbuf, Dsin, Y);
}